// Round 17
// baseline (92.609 us; speedup 1.0000x reference)
//
#include <hip/hip_runtime.h>

#define B_SZ 8
#define T_SZ 4096
#define D_SZ 1024
#define N_SZ 128
#define M_SZ (B_SZ*T_SZ)            // 32768
#define C1 32                       // gemm1 tile rows = small scan chunk
#define NC1 (T_SZ/C1)               // 128 small chunks per batch
#define C2 64                       // scan/gemm2 chunk rows
#define NC2 (T_SZ/C2)               // 64 big chunks per batch

typedef __attribute__((ext_vector_type(8))) __bf16 bf16x8;
typedef __attribute__((ext_vector_type(4))) float f32x4;
typedef __attribute__((ext_vector_type(4))) unsigned int u32x4;
typedef __attribute__((ext_vector_type(4))) float fvec4;

static __device__ __forceinline__ unsigned short f2bf(float f){
  union { float f; unsigned int u; } v; v.f = f;
  unsigned int r = v.u + 0x7fffu + ((v.u >> 16) & 1u);
  return (unsigned short)(r >> 16);
}

static __device__ __forceinline__ float bf2f(unsigned short s){
  union { unsigned int u; float f; } v; v.u = ((unsigned)s) << 16;
  return v.f;
}

static __device__ __forceinline__ void cp16(const void* g, void* l){
  __builtin_amdgcn_global_load_lds(
      (const __attribute__((address_space(1))) void*)g,
      (__attribute__((address_space(3))) void*)l, 16, 0, 0);
}

static __device__ __forceinline__ f32x4 zero4(){
  f32x4 v = {0.f, 0.f, 0.f, 0.f};
  return v;
}

static __device__ __forceinline__ bf16x8 pack8(fvec4 a, fvec4 b){
  bf16x8 v;
  v[0]=(__bf16)a.x; v[1]=(__bf16)a.y; v[2]=(__bf16)a.z; v[3]=(__bf16)a.w;
  v[4]=(__bf16)b.x; v[5]=(__bf16)b.y; v[6]=(__bf16)b.z; v[7]=(__bf16)b.w;
  return v;
}

// ---------------------------------------------------------------------------
// K0: convert weights to bf16, pre-swizzled.
// bw: [16 kchunks][128 n][64 k]; byte = c*16384 + n*128 + ((kk*2)^((n&7)<<4))
// cw: [8 dchunks][128 d][128 k]; byte = c*32768 + dd*256 + ((k*2)^((dd&15)<<4))
// ---------------------------------------------------------------------------
__global__ __launch_bounds__(256) void k_conv(const float* __restrict__ Bw,
                                              const float* __restrict__ Cw,
                                              unsigned short* __restrict__ bw,
                                              unsigned short* __restrict__ cw){
  int t = blockIdx.x*256 + threadIdx.x;   // 131072 threads total
  {
    int n = t >> 10, k = t & 1023;
    int c = k >> 6, kk = k & 63;
    unsigned byte = (unsigned)c*16384u + (unsigned)n*128u
                  + (unsigned)((kk*2) ^ ((n&7)<<4));
    bw[byte>>1] = f2bf(Bw[n*1024 + k]);
  }
  {
    int d = t >> 7, k = t & 127;
    int c = d >> 7, dd = d & 127;
    unsigned byte = (unsigned)c*32768u + (unsigned)dd*256u
                  + (unsigned)((k*2) ^ ((dd&15)<<4));
    cw[byte>>1] = f2bf(Cw[d*128 + k]);
  }
}

// ---------------------------------------------------------------------------
// GEMM1 (BM=32, grid 1024, 4 blocks/CU resident) + 32-row scan carry.
// Unchanged from the 84.6 us champion.
// ---------------------------------------------------------------------------
__global__ __launch_bounds__(256, 4) void k_gemm1c(const float* __restrict__ u,
                                                   const unsigned short* __restrict__ bw,
                                                   const float* __restrict__ Bb,
                                                   const float* __restrict__ logA,
                                                   const float* __restrict__ logdt,
                                                   unsigned short* __restrict__ Bu_bf,
                                                   float* __restrict__ carry){
  __shared__ __align__(16) char smem[20480];
  unsigned short* lA = (unsigned short*)smem;           //  4 KB phase A
  unsigned short* lB = (unsigned short*)(smem + 4096);  // 16 KB phase A
  float*          BuT = (float*)smem;                   // 16 KB after GEMM
  const int tid  = threadIdx.x;
  const int lane = tid & 63;
  const int wave = tid >> 6;
  const int bc   = blockIdx.x;      // 32-row chunk id, 0..1023
  const int m0   = bc * 32;
  const int l15  = lane & 15;
  const int lhi  = lane >> 4;
  const int rt   = (wave & 1) * 16; // row tile of this wave
  const int ct0  = (wave >> 1) * 4; // col tile base of this wave

  f32x4 acc[4];
  #pragma unroll
  for (int i=0;i<4;++i) acc[i] = zero4();

  for (int kc=0; kc<16; ++kc){
    #pragma unroll
    for (int rep=0; rep<4; ++rep){
      const char* g = (const char*)bw + kc*16384 + rep*4096 + tid*16;
      cp16(g, (char*)lB + rep*4096 + tid*16);
    }
    {
      int row = tid >> 3, ks = tid & 7;
      const float* src = u + (size_t)(m0+row)*1024 + kc*64 + ks*8;
      fvec4 f0 = *(const fvec4*)src;
      fvec4 f1 = *(const fvec4*)(src+4);
      unsigned byte = (unsigned)row*128u + (unsigned)((ks*16) ^ ((row&7)<<4));
      *(bf16x8*)((char*)lA + byte) = pack8(f0, f1);
    }
    __syncthreads();
    #pragma unroll
    for (int k0=0; k0<64; k0+=32){
      int arow = rt + l15;
      int ak = k0 + lhi*8;
      bf16x8 af = *(const bf16x8*)((const char*)lA + arow*128 + ((ak*2) ^ ((arow&7)<<4)));
      #pragma unroll
      for (int j=0;j<4;++j){
        int bn = (ct0+j)*16 + l15;
        bf16x8 bfv = *(const bf16x8*)((const char*)lB + bn*128 + ((ak*2) ^ ((bn&7)<<4)));
        acc[j] = __builtin_amdgcn_mfma_f32_16x16x32_bf16(af, bfv, acc[j], 0, 0, 0);
      }
    }
    __syncthreads();
  }

  #pragma unroll
  for (int j=0;j<4;++j){
    int n = (ct0+j)*16 + l15;
    float dt = fminf(__expf(logdt[n]), 1.f);
    float bb = Bb[n];
    #pragma unroll
    for (int r=0;r<4;++r){
      int ml = rt + lhi*4 + r;
      BuT[ml*128 + n] = (acc[j][r] + bb) * dt;
    }
  }
  __syncthreads();

  #pragma unroll
  for (int i=0;i<2;++i){
    int q = i*256 + tid;
    const float* s = BuT + q*8;
    fvec4 a = *(const fvec4*)s;
    fvec4 b = *(const fvec4*)(s+4);
    u32x4 p;
    p.x = (unsigned)f2bf(a.x) | ((unsigned)f2bf(a.y)<<16);
    p.y = (unsigned)f2bf(a.z) | ((unsigned)f2bf(a.w)<<16);
    p.z = (unsigned)f2bf(b.x) | ((unsigned)f2bf(b.y)<<16);
    p.w = (unsigned)f2bf(b.z) | ((unsigned)f2bf(b.w)<<16);
    *(u32x4*)((char*)Bu_bf + (size_t)bc*8192 + (size_t)q*16) = p;
  }

  if (tid < 128){
    int n = tid;
    float dt = fminf(__expf(logdt[n]), 1.f);
    float Ab = __expf(-__expf(logA[n]) * dt);
    float h = 0.f;
    #pragma unroll 8
    for (int j=0;j<C1;++j) h = fmaf(Ab, h, BuT[j*128 + n]);
    carry[(size_t)bc*128 + n] = h;
  }
}

// ---------------------------------------------------------------------------
// Scan: per 64-row chunk, cross-chunk prefix (32-row carries) + 64-step local
// scan reading Bu_bf; writes hs bf16 PRE-SWIZZLED for gemm2's linear cp16.
// hs: [512 chunks][64 j][128 n], byte = chunk*16384 + j*256 + ((n*2)^((j&15)<<4))
// ---------------------------------------------------------------------------
__global__ __launch_bounds__(128) void k_scan(const unsigned short* __restrict__ Bu_bf,
                                              const float* __restrict__ carry,
                                              const float* __restrict__ h0,
                                              const float* __restrict__ logA,
                                              const float* __restrict__ logdt,
                                              unsigned short* __restrict__ hs){
  const int bc = blockIdx.x;        // 64-row chunk, 0..511
  const int n  = threadIdx.x;       // 0..127
  const int b  = bc >> 6;
  const int c32 = (bc & 63) * 2;
  float dt = fminf(__expf(logdt[n]), 1.f);
  float Ad = -__expf(logA[n]) * dt;
  float Ab = __expf(Ad);
  float AL = __expf(Ad * (float)C1);
  float h = h0[b*128 + n];
  const float* cp = carry + (size_t)b*NC1*128 + n;
  for (int g=0; g<8; ++g){
    if (g*16 >= c32) break;         // block-uniform skip
    float cbuf[16];
    #pragma unroll
    for (int i=0;i<16;++i) cbuf[i] = cp[(size_t)(g*16+i)*128];
    #pragma unroll
    for (int i=0;i<16;++i){
      int idx = g*16 + i;
      h = (idx < c32) ? fmaf(AL, h, cbuf[i]) : h;
    }
  }
  const unsigned short* bp = Bu_bf + (size_t)bc*C2*128 + n;
  char* hbase = (char*)hs + (size_t)bc*16384;
  #pragma unroll 8
  for (int j=0;j<C2;++j){
    h = fmaf(Ab, h, bf2f(bp[(size_t)j*128]));
    unsigned byte = (unsigned)j*256u + (unsigned)((n*2) ^ ((j&15)<<4));
    *(unsigned short*)(hbase + byte) = f2bf(h);
  }
}

// ---------------------------------------------------------------------------
// GEMM2: lean streaming GEMM. Grid 512: bid = d*64 + mg. The 8 d-blocks of an
// m-group have bid ≡ mg (mod 8) -> same XCD -> shared hs chunks are L2-local.
// cwT (32 KB) staged ONCE per block; hs chunks double-buffered (2×16 KB);
// per iter: 4 cp16 + u-prefetch + 36 ds_reads + 32 MFMAs + epilogue + ONE
// counted vmcnt + barrier. LDS 64 KB -> 2 blocks/CU.
// ---------------------------------------------------------------------------
__global__ __launch_bounds__(256, 2) void k_gemm2(const unsigned short* __restrict__ hs,
                                                  const unsigned short* __restrict__ cw,
                                                  const float* __restrict__ u,
                                                  const float* __restrict__ Cb,
                                                  const float* __restrict__ Dp,
                                                  float* __restrict__ y){
  __shared__ __align__(16) unsigned short cwT[128*128];     // 32 KB (once)
  __shared__ __align__(16) unsigned short hsA[2][64*128];   // 2 × 16 KB
  const int tid = threadIdx.x, lane = tid & 63, wave = tid >> 6;
  const int bid = blockIdx.x;
  const int mg = bid & 63;          // m-group (512 rows)
  const int d  = bid >> 6;          // d-chunk 0..7
  const int l15 = lane & 15, lhi = lane >> 4;
  const int d0 = d*128;

  // prologue: stage cwT (8 rounds) + hs chunk 0 (4 rounds); async
  #pragma unroll
  for (int i=0;i<8;++i){
    int off = i*4096 + tid*16;
    cp16((const char*)cw + (size_t)d*32768 + off, (char*)cwT + off);
  }
  #pragma unroll
  for (int i=0;i<4;++i){
    int off = i*4096 + tid*16;
    cp16((const char*)hs + (size_t)(mg*8)*16384 + off, (char*)hsA[0] + off);
  }
  __syncthreads();                  // full drain (prologue only)

  int cur = 0;
  for (int i=0;i<8;++i){
    const int m0 = mg*512 + i*64;

    if (i < 7){                     // stage next hs chunk (4 cp16, oldest ops)
      #pragma unroll
      for (int r2=0;r2<4;++r2){
        int off = r2*4096 + tid*16;
        cp16((const char*)hs + (size_t)(mg*8+i+1)*16384 + off,
             (char*)hsA[cur^1] + off);
      }
    }

    // u prefetch (rides the VMEM pipe under the MFMA phase)
    float up[8][4];
    #pragma unroll
    for (int ct=0;ct<8;++ct){
      int dc = d0 + ct*16 + l15;
      #pragma unroll
      for (int r=0;r<4;++r){
        int m = m0 + wave*16 + lhi*4 + r;
        up[ct][r] = u[(size_t)m*1024 + dc];
      }
    }

    f32x4 acc[8];
    #pragma unroll
    for (int j=0;j<8;++j) acc[j] = zero4();

    {
      const char* hb = (const char*)hsA[cur];
      int arow = wave*16 + l15;
      #pragma unroll
      for (int k0i=0;k0i<4;++k0i){
        int ak = k0i*32 + lhi*8;
        bf16x8 af = *(const bf16x8*)(hb + arow*256 + ((ak*2) ^ ((arow&15)<<4)));
        #pragma unroll
        for (int ct=0;ct<8;++ct){
          int dn = ct*16 + l15;
          bf16x8 bfv = *(const bf16x8*)((const char*)cwT + dn*256 + ((ak*2) ^ ((dn&15)<<4)));
          acc[ct] = __builtin_amdgcn_mfma_f32_16x16x32_bf16(af, bfv, acc[ct], 0, 0, 0);
        }
      }
    }

    // epilogue: y = acc + Cb + Dp*u (u in registers)
    #pragma unroll
    for (int ct=0;ct<8;++ct){
      int dc = d0 + ct*16 + l15;
      float cb = Cb[dc], dp = Dp[dc];
      #pragma unroll
      for (int r=0;r<4;++r){
        int m = m0 + wave*16 + lhi*4 + r;
        size_t off = (size_t)m*1024 + dc;
        y[off] = acc[ct][r] + cb + dp*up[ct][r];
      }
    }

    // retire the 4 cp16s (oldest outstanding) while y-stores stay in flight;
    // barrier also guarantees all waves finished reading hsA[cur] before the
    // next iteration overwrites it.
    asm volatile("s_waitcnt vmcnt(32)" ::: "memory");
    __builtin_amdgcn_s_barrier();
    __builtin_amdgcn_sched_barrier(0);
    cur ^= 1;
  }
}

// ---------------------------------------------------------------------------
extern "C" void kernel_launch(void* const* d_in, const int* in_sizes, int n_in,
                              void* d_out, int out_size, void* d_ws, size_t ws_size,
                              hipStream_t stream){
  (void)in_sizes; (void)n_in; (void)out_size; (void)ws_size;
  const float* u     = (const float*)d_in[0];
  const float* h0    = (const float*)d_in[1];
  const float* logA  = (const float*)d_in[2];
  const float* Bw    = (const float*)d_in[3];
  const float* Bb    = (const float*)d_in[4];
  const float* Cw    = (const float*)d_in[5];
  const float* Cb    = (const float*)d_in[6];
  const float* Dp    = (const float*)d_in[7];
  const float* logdt = (const float*)d_in[8];
  float* y = (float*)d_out;

  char* ws = (char*)d_ws;
  unsigned short* Bu_bf = (unsigned short*)(ws);             //  8,388,608 B
  float*          carry = (float*)(ws + 8388608);            //    524,288 B
  unsigned short* bw    = (unsigned short*)(ws + 8912896);   //    262,144 B
  unsigned short* cw    = (unsigned short*)(ws + 9175040);   //    262,144 B
  unsigned short* hsb   = (unsigned short*)(ws + 9437184);   // 16,777,216 B
  // total ws use: 26,214,400 B

  k_conv  <<<dim3(512),  dim3(256), 0, stream>>>(Bw, Cw, bw, cw);
  k_gemm1c<<<dim3(1024), dim3(256), 0, stream>>>(u, bw, Bb, logA, logdt, Bu_bf, carry);
  k_scan  <<<dim3(512),  dim3(128), 0, stream>>>(Bu_bf, carry, h0, logA, logdt, hsb);
  k_gemm2 <<<dim3(512),  dim3(256), 0, stream>>>(hsb, cw, u, Cb, Dp, y);
}

// Round 18
// 83.770 us; speedup vs baseline: 1.1055x; 1.1055x over previous
//
#include <hip/hip_runtime.h>

#define B_SZ 8
#define T_SZ 4096
#define D_SZ 1024
#define N_SZ 128
#define M_SZ (B_SZ*T_SZ)            // 32768
#define C1 32                       // gemm1 tile rows = small scan chunk
#define NC1 (T_SZ/C1)               // 128 small chunks per batch
#define C2 64                       // gemm2 tile rows
#define NC2 (T_SZ/C2)               // 64 big chunks per batch

typedef __attribute__((ext_vector_type(8))) __bf16 bf16x8;
typedef __attribute__((ext_vector_type(4))) float f32x4;
typedef __attribute__((ext_vector_type(4))) unsigned int u32x4;
typedef __attribute__((ext_vector_type(4))) float fvec4;

static __device__ __forceinline__ unsigned short f2bf(float f){
  union { float f; unsigned int u; } v; v.f = f;
  unsigned int r = v.u + 0x7fffu + ((v.u >> 16) & 1u);
  return (unsigned short)(r >> 16);
}

static __device__ __forceinline__ float bf2f(unsigned short s){
  union { unsigned int u; float f; } v; v.u = ((unsigned)s) << 16;
  return v.f;
}

static __device__ __forceinline__ void cp16(const void* g, void* l){
  __builtin_amdgcn_global_load_lds(
      (const __attribute__((address_space(1))) void*)g,
      (__attribute__((address_space(3))) void*)l, 16, 0, 0);
}

static __device__ __forceinline__ f32x4 zero4(){
  f32x4 v = {0.f, 0.f, 0.f, 0.f};
  return v;
}

static __device__ __forceinline__ bf16x8 pack8(fvec4 a, fvec4 b){
  bf16x8 v;
  v[0]=(__bf16)a.x; v[1]=(__bf16)a.y; v[2]=(__bf16)a.z; v[3]=(__bf16)a.w;
  v[4]=(__bf16)b.x; v[5]=(__bf16)b.y; v[6]=(__bf16)b.z; v[7]=(__bf16)b.w;
  return v;
}

// ---------------------------------------------------------------------------
// K0: convert weights to bf16, pre-swizzled.
// bw: [16 kchunks][128 n][64 k]; byte = c*16384 + n*128 + ((kk*2)^((n&7)<<4))
// cw: [8 dchunks][128 d][128 k]; byte = c*32768 + dd*256 + ((k*2)^((dd&15)<<4))
// ---------------------------------------------------------------------------
__global__ __launch_bounds__(256) void k_conv(const float* __restrict__ Bw,
                                              const float* __restrict__ Cw,
                                              unsigned short* __restrict__ bw,
                                              unsigned short* __restrict__ cw){
  int t = blockIdx.x*256 + threadIdx.x;   // 131072 threads total
  {
    int n = t >> 10, k = t & 1023;
    int c = k >> 6, kk = k & 63;
    unsigned byte = (unsigned)c*16384u + (unsigned)n*128u
                  + (unsigned)((kk*2) ^ ((n&7)<<4));
    bw[byte>>1] = f2bf(Bw[n*1024 + k]);
  }
  {
    int d = t >> 7, k = t & 127;
    int c = d >> 7, dd = d & 127;
    unsigned byte = (unsigned)c*32768u + (unsigned)dd*256u
                  + (unsigned)((k*2) ^ ((dd&15)<<4));
    cw[byte>>1] = f2bf(Cw[d*128 + k]);
  }
}

// ---------------------------------------------------------------------------
// GEMM1 (BM=32, grid 1024, 4 blocks/CU resident) + 32-row scan carry.
// ---------------------------------------------------------------------------
__global__ __launch_bounds__(256, 4) void k_gemm1c(const float* __restrict__ u,
                                                   const unsigned short* __restrict__ bw,
                                                   const float* __restrict__ Bb,
                                                   const float* __restrict__ logA,
                                                   const float* __restrict__ logdt,
                                                   unsigned short* __restrict__ Bu_bf,
                                                   float* __restrict__ carry){
  __shared__ __align__(16) char smem[20480];
  unsigned short* lA = (unsigned short*)smem;           //  4 KB phase A
  unsigned short* lB = (unsigned short*)(smem + 4096);  // 16 KB phase A
  float*          BuT = (float*)smem;                   // 16 KB after GEMM
  const int tid  = threadIdx.x;
  const int lane = tid & 63;
  const int wave = tid >> 6;
  const int bc   = blockIdx.x;      // 32-row chunk id, 0..1023
  const int m0   = bc * 32;
  const int l15  = lane & 15;
  const int lhi  = lane >> 4;
  const int rt   = (wave & 1) * 16; // row tile of this wave
  const int ct0  = (wave >> 1) * 4; // col tile base of this wave

  f32x4 acc[4];
  #pragma unroll
  for (int i=0;i<4;++i) acc[i] = zero4();

  for (int kc=0; kc<16; ++kc){
    #pragma unroll
    for (int rep=0; rep<4; ++rep){
      const char* g = (const char*)bw + kc*16384 + rep*4096 + tid*16;
      cp16(g, (char*)lB + rep*4096 + tid*16);
    }
    {
      int row = tid >> 3, ks = tid & 7;
      const float* src = u + (size_t)(m0+row)*1024 + kc*64 + ks*8;
      fvec4 f0 = *(const fvec4*)src;
      fvec4 f1 = *(const fvec4*)(src+4);
      unsigned byte = (unsigned)row*128u + (unsigned)((ks*16) ^ ((row&7)<<4));
      *(bf16x8*)((char*)lA + byte) = pack8(f0, f1);
    }
    __syncthreads();
    #pragma unroll
    for (int k0=0; k0<64; k0+=32){
      int arow = rt + l15;
      int ak = k0 + lhi*8;
      bf16x8 af = *(const bf16x8*)((const char*)lA + arow*128 + ((ak*2) ^ ((arow&7)<<4)));
      #pragma unroll
      for (int j=0;j<4;++j){
        int bn = (ct0+j)*16 + l15;
        bf16x8 bfv = *(const bf16x8*)((const char*)lB + bn*128 + ((ak*2) ^ ((bn&7)<<4)));
        acc[j] = __builtin_amdgcn_mfma_f32_16x16x32_bf16(af, bfv, acc[j], 0, 0, 0);
      }
    }
    __syncthreads();
  }

  #pragma unroll
  for (int j=0;j<4;++j){
    int n = (ct0+j)*16 + l15;
    float dt = fminf(__expf(logdt[n]), 1.f);
    float bb = Bb[n];
    #pragma unroll
    for (int r=0;r<4;++r){
      int ml = rt + lhi*4 + r;
      BuT[ml*128 + n] = (acc[j][r] + bb) * dt;
    }
  }
  __syncthreads();

  #pragma unroll
  for (int i=0;i<2;++i){
    int q = i*256 + tid;
    const float* s = BuT + q*8;
    fvec4 a = *(const fvec4*)s;
    fvec4 b = *(const fvec4*)(s+4);
    u32x4 p;
    p.x = (unsigned)f2bf(a.x) | ((unsigned)f2bf(a.y)<<16);
    p.y = (unsigned)f2bf(a.z) | ((unsigned)f2bf(a.w)<<16);
    p.z = (unsigned)f2bf(b.x) | ((unsigned)f2bf(b.y)<<16);
    p.w = (unsigned)f2bf(b.z) | ((unsigned)f2bf(b.w)<<16);
    *(u32x4*)((char*)Bu_bf + (size_t)bc*8192 + (size_t)q*16) = p;
  }

  if (tid < 128){
    int n = tid;
    float dt = fminf(__expf(logdt[n]), 1.f);
    float Ab = __expf(-__expf(logA[n]) * dt);
    float h = 0.f;
    #pragma unroll 8
    for (int j=0;j<C1;++j) h = fmaf(Ab, h, BuT[j*128 + n]);
    carry[(size_t)bc*128 + n] = h;
  }
}

// ---------------------------------------------------------------------------
// GEMM2 + prefix + scan — the 84.6 us champion (R14): shared cwT staged per
// d-iteration, u-tile prefetched at the TOP of each d-iteration so the 32
// u-loads ride the VMEM pipe under the LDS/MFMA phase.
// ---------------------------------------------------------------------------
__global__ __launch_bounds__(256) void k_gemm2s(const unsigned short* __restrict__ Bu_bf,
                                                const float* __restrict__ carry,
                                                const unsigned short* __restrict__ cw,
                                                const float* __restrict__ u,
                                                const float* __restrict__ h0,
                                                const float* __restrict__ Cb,
                                                const float* __restrict__ Dp,
                                                const float* __restrict__ logA,
                                                const float* __restrict__ logdt,
                                                float* __restrict__ y){
  __shared__ __align__(16) unsigned short BuT[64*128];      // 16 KB bf16 linear
  __shared__ __align__(16) unsigned short hsT[64*128];      // 16 KB swizzled
  __shared__ __align__(16) unsigned short cwT[128*128];     // 32 KB swizzled
  const int tid = threadIdx.x, lane = tid & 63, wave = tid >> 6;
  const int bc = blockIdx.x;
  const int m0 = bc * 64;
  const int l15 = lane & 15, lhi = lane >> 4;

  // stage Bu tile (4 rounds) + cw chunk 0 (8 rounds); async, drained at barrier
  #pragma unroll
  for (int i=0;i<4;++i){
    int off = i*4096 + tid*16;
    cp16((const char*)Bu_bf + (size_t)bc*16384 + off, (char*)BuT + off);
  }
  #pragma unroll
  for (int i=0;i<8;++i){
    int off = i*4096 + tid*16;
    cp16((const char*)cw + off, (char*)cwT + off);
  }

  // cross-chunk prefix over 32-row carries (batched, block-uniform skip);
  // overlaps with the async staging above.
  float hreg = 0.f, Ab = 0.f;
  if (tid < 128){
    int n = tid;
    int b = bc >> 6;
    int c32 = (bc & 63) * 2;         // # of 32-row chunks before this tile
    float dt = fminf(__expf(logdt[n]), 1.f);
    float Ad = -__expf(logA[n]) * dt;
    Ab = __expf(Ad);
    float AL = __expf(Ad * (float)C1);
    float h = h0[b*128 + n];
    const float* cp = carry + (size_t)b*NC1*128 + n;
    for (int g=0; g<8; ++g){
      if (g*16 >= c32) break;        // block-uniform skip
      float cbuf[16];
      #pragma unroll
      for (int i=0;i<16;++i) cbuf[i] = cp[(size_t)(g*16+i)*128];
      #pragma unroll
      for (int i=0;i<16;++i){
        int idx = g*16 + i;
        h = (idx < c32) ? fmaf(AL, h, cbuf[i]) : h;
      }
    }
    hreg = h;
  }
  __syncthreads();

  // local scan (bf16 Bu from LDS) -> swizzled bf16 hsT
  if (tid < 128){
    int n = tid;
    float h = hreg;
    #pragma unroll 8
    for (int j=0;j<C2;++j){
      h = fmaf(Ab, h, bf2f(BuT[j*128 + n]));
      unsigned byte = (unsigned)j*256u + (unsigned)((n*2) ^ ((j&15)<<4));
      *(unsigned short*)((char*)hsT + byte) = f2bf(h);
    }
  }
  __syncthreads();

  for (int d=0; d<8; ++d){
    const int d0 = d*128;

    // u prefetch for this d-iteration: independent of LDS, issues onto the
    // otherwise-idle VMEM pipe and completes under the MFMA phase.
    float up[8][4];
    #pragma unroll
    for (int ct=0;ct<8;++ct){
      int dc = d0 + ct*16 + l15;
      #pragma unroll
      for (int r=0;r<4;++r){
        int m = m0 + wave*16 + lhi*4 + r;
        up[ct][r] = u[(size_t)m*1024 + dc];
      }
    }

    f32x4 acc[8];
    #pragma unroll
    for (int i=0;i<8;++i) acc[i] = zero4();

    #pragma unroll
    for (int k0=0;k0<128;k0+=32){
      int arow = wave*16 + l15;
      int ak = k0 + lhi*8;
      bf16x8 af = *(const bf16x8*)((const char*)hsT + arow*256 + ((ak*2) ^ ((arow&15)<<4)));
      #pragma unroll
      for (int ct=0;ct<8;++ct){
        int dn = ct*16 + l15;
        bf16x8 bfv = *(const bf16x8*)((const char*)cwT + dn*256 + ((ak*2) ^ ((dn&15)<<4)));
        acc[ct] = __builtin_amdgcn_mfma_f32_16x16x32_bf16(af, bfv, acc[ct], 0, 0, 0);
      }
    }
    __syncthreads();              // all waves done reading cwT

    if (d < 7){                   // stage next cw chunk (async)
      #pragma unroll
      for (int i=0;i<8;++i){
        int off = (wave*8 + i)*1024 + lane*16;
        cp16((const char*)cw + (size_t)(d+1)*32768 + off, (char*)cwT + off);
      }
    }

    // epilogue: y = acc + Cb + Dp*u (u already in registers)
    #pragma unroll
    for (int ct=0;ct<8;++ct){
      int dc = d0 + ct*16 + l15;
      float cb = Cb[dc], dp = Dp[dc];
      #pragma unroll
      for (int r=0;r<4;++r){
        int m = m0 + wave*16 + lhi*4 + r;
        size_t off = (size_t)m*1024 + dc;
        y[off] = acc[ct][r] + cb + dp*up[ct][r];
      }
    }
    __syncthreads();              // drains cp16s before next MFMA
  }
}

// ---------------------------------------------------------------------------
extern "C" void kernel_launch(void* const* d_in, const int* in_sizes, int n_in,
                              void* d_out, int out_size, void* d_ws, size_t ws_size,
                              hipStream_t stream){
  (void)in_sizes; (void)n_in; (void)out_size; (void)ws_size;
  const float* u     = (const float*)d_in[0];
  const float* h0    = (const float*)d_in[1];
  const float* logA  = (const float*)d_in[2];
  const float* Bw    = (const float*)d_in[3];
  const float* Bb    = (const float*)d_in[4];
  const float* Cw    = (const float*)d_in[5];
  const float* Cb    = (const float*)d_in[6];
  const float* Dp    = (const float*)d_in[7];
  const float* logdt = (const float*)d_in[8];
  float* y = (float*)d_out;

  char* ws = (char*)d_ws;
  unsigned short* Bu_bf = (unsigned short*)(ws);             // 8,388,608 B
  float*          carry = (float*)(ws + 8388608);            //   524,288 B
  unsigned short* bw    = (unsigned short*)(ws + 8912896);   //   262,144 B
  unsigned short* cw    = (unsigned short*)(ws + 9175040);   //   262,144 B
  // total ws use: 9,437,184 B

  k_conv  <<<dim3(512),  dim3(256), 0, stream>>>(Bw, Cw, bw, cw);
  k_gemm1c<<<dim3(1024), dim3(256), 0, stream>>>(u, bw, Bb, logA, logdt, Bu_bf, carry);
  k_gemm2s<<<dim3(512),  dim3(256), 0, stream>>>(Bu_bf, carry, cw, u, h0, Cb, Dp,
                                                 logA, logdt, y);
}